// Round 1
// baseline (834.596 us; speedup 1.0000x reference)
//
#include <hip/hip_runtime.h>
#include <hip/hip_bf16.h>

#define BSZ 16384
#define DIM 512
#define NEMB 8192
#define NEG 0.01f
#define NSPLIT 8

typedef __attribute__((ext_vector_type(8))) short short8;
typedef __attribute__((ext_vector_type(4))) float f32x4;

typedef const __attribute__((address_space(1))) void GVT;
typedef __attribute__((address_space(3))) void LVT;

__device__ __forceinline__ void gl_lds16(const void* g, void* l) {
    __builtin_amdgcn_global_load_lds((GVT*)g, (LVT*)l, 16, 0, 0);
}

__device__ __forceinline__ float bf2f(unsigned short u) {
    union { unsigned int i; float f; } c; c.i = ((unsigned int)u) << 16; return c.f;
}
__device__ __forceinline__ unsigned short f2bf(float f) {
    union { __hip_bfloat16 h; unsigned short u; } c; c.h = __float2bfloat16(f); return c.u;
}

// ---------------- fp32 -> bf16 convert (vectorized) ----------------
__global__ void k_convert(const float* __restrict__ in, unsigned short* __restrict__ out, int n4) {
    for (int i = blockIdx.x * blockDim.x + threadIdx.x; i < n4; i += gridDim.x * blockDim.x) {
        float4 v = ((const float4*)in)[i];
        ushort4 o;
        o.x = f2bf(v.x); o.y = f2bf(v.y); o.z = f2bf(v.z); o.w = f2bf(v.w);
        ((ushort4*)out)[i] = o;
    }
}

// ---------------- embedding row norms (fp32) ----------------
__global__ void k_enorm(const float* __restrict__ emb, float* __restrict__ enorm) {
    int row = blockIdx.x * 4 + (threadIdx.x >> 6);
    int lane = threadIdx.x & 63;
    const float4* p = (const float4*)(emb + row * DIM) + lane * 2;
    float4 a = p[0], b = p[1];
    float s = a.x*a.x + a.y*a.y + a.z*a.z + a.w*a.w
            + b.x*b.x + b.y*b.y + b.z*b.z + b.w*b.w;
    #pragma unroll
    for (int d = 1; d < 64; d <<= 1) s += __shfl_xor(s, d);
    if (lane == 0) enorm[row] = s;
}

// ---------------- h = LeakyReLU(eeg @ W1^T + b1), bf16 out ----------------
__launch_bounds__(256, 2)
__global__ void k_hgemm(const unsigned short* __restrict__ A,   // eeg bf16 [BSZ][DIM]
                        const unsigned short* __restrict__ B,   // W1  bf16 [DIM][DIM]
                        const float* __restrict__ b1,
                        unsigned short* __restrict__ H) {
    __shared__ __align__(16) unsigned short sA[4096], sB[4096];
    int tid = threadIdx.x;
    int w = tid >> 6, lane = tid & 63;
    int wr = w >> 1, wc = w & 1;
    int lquad = lane >> 4, l15 = lane & 15;
    int mt = blockIdx.x >> 2, nt = blockIdx.x & 3;
    int m0 = mt * 128, n0 = nt * 128;

    int e0 = w * 512 + lane * 8;
    int r0 = e0 >> 5, ce = e0 & 31;
    const unsigned short* gA0 = A + (m0 + r0) * DIM + ce;
    const unsigned short* gA1 = gA0 + 64 * DIM;
    const unsigned short* gB0 = B + (n0 + r0) * DIM + ce;
    const unsigned short* gB1 = gB0 + 64 * DIM;
    unsigned short* lA0 = sA + w * 512;  unsigned short* lA1 = sA + (w + 4) * 512;
    unsigned short* lB0 = sB + w * 512;  unsigned short* lB1 = sB + (w + 4) * 512;

    int offA[4], offB[4];
    #pragma unroll
    for (int i = 0; i < 4; i++) {
        offA[i] = (wr * 64 + i * 16 + l15) * 32 + lquad * 8;
        offB[i] = (wc * 64 + i * 16 + l15) * 32 + lquad * 8;
    }

    f32x4 acc[4][4];
    #pragma unroll
    for (int mi = 0; mi < 4; mi++)
        #pragma unroll
        for (int ni = 0; ni < 4; ni++) acc[mi][ni] = 0;

    for (int kk = 0; kk < 16; kk++) {
        gl_lds16(gA0, lA0); gl_lds16(gA1, lA1);
        gl_lds16(gB0, lB0); gl_lds16(gB1, lB1);
        gA0 += 32; gA1 += 32; gB0 += 32; gB1 += 32;
        __syncthreads();
        short8 af[4], bf_[4];
        #pragma unroll
        for (int i = 0; i < 4; i++) {
            af[i]  = *(const short8*)&sA[offA[i]];
            bf_[i] = *(const short8*)&sB[offB[i]];
        }
        #pragma unroll
        for (int mi = 0; mi < 4; mi++)
            #pragma unroll
            for (int ni = 0; ni < 4; ni++)
                acc[mi][ni] = __builtin_amdgcn_mfma_f32_16x16x32_bf16(af[mi], bf_[ni], acc[mi][ni], 0, 0, 0);
        __syncthreads();
    }

    #pragma unroll
    for (int ni = 0; ni < 4; ni++) {
        int col = n0 + wc * 64 + ni * 16 + l15;
        float bv = b1[col];
        #pragma unroll
        for (int mi = 0; mi < 4; mi++) {
            int rowb = m0 + wr * 64 + mi * 16 + lquad * 4;
            #pragma unroll
            for (int rg = 0; rg < 4; rg++) {
                float v = acc[mi][ni][rg] + bv;
                v = v >= 0.f ? v : NEG * v;
                H[(rowb + rg) * DIM + col] = f2bf(v);
            }
        }
    }
}

// ---------------- fused dual GEMM + online row stats ----------------
__launch_bounds__(256, 2)
__global__ void k_dual(const unsigned short* __restrict__ Amel,
                       const unsigned short* __restrict__ Ah,
                       const unsigned short* __restrict__ Bemb,
                       const unsigned short* __restrict__ Bw2,
                       const float* __restrict__ enorm,
                       const float* __restrict__ b2,
                       float* __restrict__ p_m, float* __restrict__ p_l,
                       float* __restrict__ p_minv,
                       int* __restrict__ p_maxi, int* __restrict__ p_mini) {
    __shared__ __align__(16) unsigned short sMel[4096], sH[4096], sEmb[4096], sW2[4096];
    __shared__ float st_m[256], st_l[256], st_minv[256];
    __shared__ int st_maxi[256], st_mini[256];

    int tid = threadIdx.x;
    st_m[tid] = -1e30f; st_l[tid] = 0.f; st_minv[tid] = 1e30f;
    st_maxi[tid] = 0;   st_mini[tid] = 0;

    int w = tid >> 6, lane = tid & 63;
    int wr = w >> 1, wc = w & 1;
    int lquad = lane >> 4, l15 = lane & 15;

    int mt = blockIdx.x >> 3, split = blockIdx.x & 7;
    int m0 = mt * 128;
    int nbase = split * (NEMB / NSPLIT);

    int e0 = w * 512 + lane * 8;
    int r0 = e0 >> 5, ce = e0 & 31;
    const unsigned short* gM = Amel + (m0 + r0) * DIM + ce;
    const unsigned short* gH = Ah   + (m0 + r0) * DIM + ce;
    unsigned short* lM0 = sMel + w * 512; unsigned short* lM1 = sMel + (w + 4) * 512;
    unsigned short* lH0 = sH   + w * 512; unsigned short* lH1 = sH   + (w + 4) * 512;
    unsigned short* lE0 = sEmb + w * 512; unsigned short* lE1 = sEmb + (w + 4) * 512;
    unsigned short* lW0 = sW2  + w * 512; unsigned short* lW1 = sW2  + (w + 4) * 512;

    int offA[4], offB[4];
    #pragma unroll
    for (int i = 0; i < 4; i++) {
        offA[i] = (wr * 64 + i * 16 + l15) * 32 + lquad * 8;
        offB[i] = (wc * 64 + i * 16 + l15) * 32 + lquad * 8;
    }

    for (int nt = 0; nt < 8; nt++) {
        int c0 = nbase + nt * 128;
        const unsigned short* gE = Bemb + (c0 + r0) * DIM + ce;
        const unsigned short* gW = Bw2  + (c0 + r0) * DIM + ce;
        const unsigned short* aM = gM;
        const unsigned short* aH = gH;

        f32x4 acc1[4][4], acc2[4][4];
        #pragma unroll
        for (int mi = 0; mi < 4; mi++)
            #pragma unroll
            for (int ni = 0; ni < 4; ni++) { acc1[mi][ni] = 0; acc2[mi][ni] = 0; }

        for (int kk = 0; kk < 16; kk++) {
            gl_lds16(aM, lM0); gl_lds16(aM + 64 * DIM, lM1);
            gl_lds16(aH, lH0); gl_lds16(aH + 64 * DIM, lH1);
            gl_lds16(gE, lE0); gl_lds16(gE + 64 * DIM, lE1);
            gl_lds16(gW, lW0); gl_lds16(gW + 64 * DIM, lW1);
            aM += 32; aH += 32; gE += 32; gW += 32;
            __syncthreads();
            short8 am[4], ah[4], be[4], bw[4];
            #pragma unroll
            for (int i = 0; i < 4; i++) {
                am[i] = *(const short8*)&sMel[offA[i]];
                ah[i] = *(const short8*)&sH[offA[i]];
                be[i] = *(const short8*)&sEmb[offB[i]];
                bw[i] = *(const short8*)&sW2[offB[i]];
            }
            #pragma unroll
            for (int mi = 0; mi < 4; mi++)
                #pragma unroll
                for (int ni = 0; ni < 4; ni++) {
                    acc1[mi][ni] = __builtin_amdgcn_mfma_f32_16x16x32_bf16(am[mi], be[ni], acc1[mi][ni], 0, 0, 0);
                    acc2[mi][ni] = __builtin_amdgcn_mfma_f32_16x16x32_bf16(ah[mi], bw[ni], acc2[mi][ni], 0, 0, 0);
                }
            __syncthreads();
        }

        // epilogue: per-row online stats over this 128-col tile
        float en[4], bb[4]; int coln[4];
        #pragma unroll
        for (int ni = 0; ni < 4; ni++) {
            coln[ni] = c0 + wc * 64 + ni * 16 + l15;
            en[ni] = enorm[coln[ni]];
            bb[ni] = b2[coln[ni]];
        }
        #pragma unroll
        for (int mi = 0; mi < 4; mi++) {
            #pragma unroll
            for (int rg = 0; rg < 4; rg++) {
                float lg[4];
                float mx = -1e30f; int mxi = 0;
                float mn = 1e30f;  int mni = 0;
                #pragma unroll
                for (int ni = 0; ni < 4; ni++) {
                    float logit = acc2[mi][ni][rg] + bb[ni];
                    float dist  = fmaf(-2.f, acc1[mi][ni][rg], en[ni]);
                    lg[ni] = logit;
                    if (logit > mx) { mx = logit; mxi = coln[ni]; }
                    if (dist  < mn) { mn = dist;  mni = coln[ni]; }
                }
                #pragma unroll
                for (int d = 1; d < 16; d <<= 1) {
                    float omx = __shfl_xor(mx, d); int omxi = __shfl_xor(mxi, d);
                    if (omx > mx || (omx == mx && omxi < mxi)) { mx = omx; mxi = omxi; }
                    float omn = __shfl_xor(mn, d); int omni = __shfl_xor(mni, d);
                    if (omn < mn || (omn == mn && omni < mni)) { mn = omn; mni = omni; }
                }
                float s = 0.f;
                #pragma unroll
                for (int ni = 0; ni < 4; ni++) s += __expf(lg[ni] - mx);
                #pragma unroll
                for (int d = 1; d < 16; d <<= 1) s += __shfl_xor(s, d);
                if (l15 == 0) {
                    int r2 = (wr * 64 + mi * 16 + lquad * 4 + rg) * 2 + wc;
                    float mo = st_m[r2];
                    if (mx > mo || (mx == mo && mxi < st_maxi[r2])) st_maxi[r2] = mxi;
                    float mnew = fmaxf(mo, mx);
                    st_l[r2] = st_l[r2] * __expf(mo - mnew) + s * __expf(mx - mnew);
                    st_m[r2] = mnew;
                    if (mn < st_minv[r2]) { st_minv[r2] = mn; st_mini[r2] = mni; }
                }
            }
        }
    }

    __syncthreads();
    if (tid < 128) {
        int r2 = tid * 2;
        float ma = st_m[r2], mb = st_m[r2 + 1];
        int   ia = st_maxi[r2], ib = st_maxi[r2 + 1];
        float M; int MI;
        if (mb > ma || (mb == ma && ib < ia)) { M = mb; MI = ib; } else { M = ma; MI = ia; }
        float L = st_l[r2] * __expf(ma - M) + st_l[r2 + 1] * __expf(mb - M);
        float va = st_minv[r2], vb = st_minv[r2 + 1];
        int   ja = st_mini[r2], jb = st_mini[r2 + 1];
        float V; int VI;
        if (vb < va || (vb == va && jb < ja)) { V = vb; VI = jb; } else { V = va; VI = ja; }
        int pidx = split * BSZ + m0 + tid;
        p_m[pidx] = M; p_l[pidx] = L; p_maxi[pidx] = MI;
        p_minv[pidx] = V; p_mini[pidx] = VI;
    }
}

// ---------------- merge split partials per row ----------------
__global__ void k_merge(const float* __restrict__ p_m, const float* __restrict__ p_l,
                        const float* __restrict__ p_minv,
                        const int* __restrict__ p_maxi, const int* __restrict__ p_mini,
                        int* __restrict__ mel_idx, float* __restrict__ lse,
                        float* __restrict__ match) {
    int r = blockIdx.x * blockDim.x + threadIdx.x;
    if (r >= BSZ) return;
    float M = -1e30f; int MI = 0; float V = 1e30f; int VI = 0;
    for (int s = 0; s < NSPLIT; s++) {
        float m = p_m[s * BSZ + r]; int mi = p_maxi[s * BSZ + r];
        if (m > M || (m == M && mi < MI)) { M = m; MI = mi; }
        float v = p_minv[s * BSZ + r]; int vi = p_mini[s * BSZ + r];
        if (v < V || (v == V && vi < VI)) { V = v; VI = vi; }
    }
    float L = 0.f;
    for (int s = 0; s < NSPLIT; s++) L += p_l[s * BSZ + r] * __expf(p_m[s * BSZ + r] - M);
    mel_idx[r] = VI;
    lse[r] = M + __logf(L);
    match[r] = (MI == VI) ? 1.f : 0.f;
}

// ---------------- gather picked logit, per-row loss ----------------
__device__ __forceinline__ float dot2bf(unsigned int h, unsigned int w) {
    return bf2f((unsigned short)(h & 0xffff)) * bf2f((unsigned short)(w & 0xffff))
         + bf2f((unsigned short)(h >> 16))    * bf2f((unsigned short)(w >> 16));
}

__global__ void k_gather(const unsigned short* __restrict__ H,
                         const unsigned short* __restrict__ W2b,
                         const float* __restrict__ b2,
                         const int* __restrict__ mel_idx,
                         const float* __restrict__ lse,
                         float* __restrict__ loss) {
    int r = blockIdx.x * 4 + (threadIdx.x >> 6);
    int lane = threadIdx.x & 63;
    int idx = mel_idx[r];
    uint4 hv = *(const uint4*)(H + r * DIM + lane * 8);
    uint4 wv = *(const uint4*)(W2b + idx * DIM + lane * 8);
    float s = dot2bf(hv.x, wv.x) + dot2bf(hv.y, wv.y) + dot2bf(hv.z, wv.z) + dot2bf(hv.w, wv.w);
    #pragma unroll
    for (int d = 1; d < 64; d <<= 1) s += __shfl_xor(s, d);
    if (lane == 0) loss[r] = lse[r] - (s + b2[idx]);
}

// ---------------- final scalar reduction ----------------
__global__ void k_reduce(const float* __restrict__ loss, const float* __restrict__ match,
                         float* __restrict__ out) {
    __shared__ float sl[256], sm[256];
    int tid = threadIdx.x;
    float a = 0.f, b = 0.f;
    for (int i = tid; i < BSZ; i += 256) { a += loss[i]; b += match[i]; }
    sl[tid] = a; sm[tid] = b;
    __syncthreads();
    for (int s = 128; s > 0; s >>= 1) {
        if (tid < s) { sl[tid] += sl[tid + s]; sm[tid] += sm[tid + s]; }
        __syncthreads();
    }
    if (tid == 0) { out[0] = sl[0] / (float)BSZ; out[1] = sm[0] / (float)BSZ; }
}

extern "C" void kernel_launch(void* const* d_in, const int* in_sizes, int n_in,
                              void* d_out, int out_size, void* d_ws, size_t ws_size,
                              hipStream_t stream) {
    const float* eeg = (const float*)d_in[0];
    const float* mel = (const float*)d_in[1];
    const float* emb = (const float*)d_in[2];
    const float* W1  = (const float*)d_in[3];
    const float* b1  = (const float*)d_in[4];
    const float* W2  = (const float*)d_in[5];
    const float* b2  = (const float*)d_in[6];
    float* out = (float*)d_out;

    unsigned short* ws_mel = (unsigned short*)d_ws;          // [BSZ*DIM]
    unsigned short* ws_eeg = ws_mel + (size_t)BSZ * DIM;
    unsigned short* ws_h   = ws_eeg + (size_t)BSZ * DIM;
    unsigned short* ws_emb = ws_h   + (size_t)BSZ * DIM;
    unsigned short* ws_w2  = ws_emb + (size_t)NEMB * DIM;
    unsigned short* ws_w1  = ws_w2  + (size_t)NEMB * DIM;
    float* ws_en  = (float*)(ws_w1 + (size_t)DIM * DIM);
    float* p_m    = ws_en + NEMB;
    float* p_l    = p_m + (size_t)NSPLIT * BSZ;
    float* p_minv = p_l + (size_t)NSPLIT * BSZ;
    int*   p_maxi = (int*)(p_minv + (size_t)NSPLIT * BSZ);
    int*   p_mini = p_maxi + (size_t)NSPLIT * BSZ;
    int*   mel_i  = p_mini + (size_t)NSPLIT * BSZ;
    float* lse    = (float*)(mel_i + BSZ);
    float* match  = lse + BSZ;
    float* loss   = match + BSZ;

    k_convert<<<256, 256, 0, stream>>>(mel, ws_mel, BSZ * DIM / 4);
    k_convert<<<256, 256, 0, stream>>>(eeg, ws_eeg, BSZ * DIM / 4);
    k_convert<<<128, 256, 0, stream>>>(emb, ws_emb, NEMB * DIM / 4);
    k_convert<<<128, 256, 0, stream>>>(W2, ws_w2, NEMB * DIM / 4);
    k_convert<<<32, 256, 0, stream>>>(W1, ws_w1, DIM * DIM / 4);
    k_enorm<<<NEMB / 4, 256, 0, stream>>>(emb, ws_en);
    k_hgemm<<<(BSZ / 128) * (DIM / 128), 256, 0, stream>>>(ws_eeg, ws_w1, b1, ws_h);
    k_dual<<<(BSZ / 128) * NSPLIT, 256, 0, stream>>>(ws_mel, ws_h, ws_emb, ws_w2, ws_en, b2,
                                                     p_m, p_l, p_minv, p_maxi, p_mini);
    k_merge<<<BSZ / 256, 256, 0, stream>>>(p_m, p_l, p_minv, p_maxi, p_mini, mel_i, lse, match);
    k_gather<<<BSZ / 4, 256, 0, stream>>>(ws_h, ws_w2, b2, mel_i, lse, loss);
    k_reduce<<<1, 256, 0, stream>>>(loss, match, out);
}

// Round 2
// 592.440 us; speedup vs baseline: 1.4087x; 1.4087x over previous
//
#include <hip/hip_runtime.h>
#include <hip/hip_bf16.h>

#define BSZ 16384
#define DIM 512
#define NEMB 8192
#define NEG 0.01f
#define NSPLIT 8

typedef __attribute__((ext_vector_type(8))) short short8;
typedef __attribute__((ext_vector_type(4))) float f32x4;

typedef const __attribute__((address_space(1))) void GVT;
typedef __attribute__((address_space(3))) void LVT;

__device__ __forceinline__ void gl_lds16(const void* g, void* l) {
    __builtin_amdgcn_global_load_lds((GVT*)g, (LVT*)l, 16, 0, 0);
}

__device__ __forceinline__ float bf2f(unsigned short u) {
    union { unsigned int i; float f; } c; c.i = ((unsigned int)u) << 16; return c.f;
}
__device__ __forceinline__ unsigned short f2bf(float f) {
    union { __hip_bfloat16 h; unsigned short u; } c; c.h = __float2bfloat16(f); return c.u;
}
// monotone-orderable uint key for a float
__device__ __forceinline__ unsigned int fkey(float f) {
    unsigned int u = __float_as_uint(f);
    return u ^ ((unsigned int)((int)u >> 31) | 0x80000000u);
}

// ---------------- fused fp32 -> bf16 convert for all 5 tensors ----------------
__global__ void k_convert_all(const float* __restrict__ eeg, const float* __restrict__ mel,
                              const float* __restrict__ emb, const float* __restrict__ W2,
                              const float* __restrict__ W1,
                              unsigned short* __restrict__ o_eeg, unsigned short* __restrict__ o_mel,
                              unsigned short* __restrict__ o_emb, unsigned short* __restrict__ o_w2,
                              unsigned short* __restrict__ o_w1) {
    const int n_big = BSZ * DIM / 4;
    const int n_mid = NEMB * DIM / 4;
    const int n_w1  = DIM * DIM / 4;
    const int total = n_big * 2 + n_mid * 2 + n_w1;
    for (int i = blockIdx.x * blockDim.x + threadIdx.x; i < total; i += gridDim.x * blockDim.x) {
        const float* src; unsigned short* dst; int j = i;
        if (j < n_big) { src = eeg; dst = o_eeg; }
        else if ((j -= n_big) < n_big) { src = mel; dst = o_mel; }
        else if ((j -= n_big) < n_mid) { src = emb; dst = o_emb; }
        else if ((j -= n_mid) < n_mid) { src = W2; dst = o_w2; }
        else { j -= n_mid; src = W1; dst = o_w1; }
        float4 v = ((const float4*)src)[j];
        ushort4 o;
        o.x = f2bf(v.x); o.y = f2bf(v.y); o.z = f2bf(v.z); o.w = f2bf(v.w);
        ((ushort4*)dst)[j] = o;
    }
}

// ---------------- embedding row norms (fp32) ----------------
__global__ void k_enorm(const float* __restrict__ emb, float* __restrict__ enorm) {
    int row = blockIdx.x * 4 + (threadIdx.x >> 6);
    int lane = threadIdx.x & 63;
    const float4* p = (const float4*)(emb + row * DIM) + lane * 2;
    float4 a = p[0], b = p[1];
    float s = a.x*a.x + a.y*a.y + a.z*a.z + a.w*a.w
            + b.x*b.x + b.y*b.y + b.z*b.z + b.w*b.w;
    #pragma unroll
    for (int d = 1; d < 64; d <<= 1) s += __shfl_xor(s, d);
    if (lane == 0) enorm[row] = s;
}

// ---------------- h = LeakyReLU(eeg @ W1^T + b1), bf16 out ----------------
__launch_bounds__(256, 2)
__global__ void k_hgemm(const unsigned short* __restrict__ A,
                        const unsigned short* __restrict__ B,
                        const float* __restrict__ b1,
                        unsigned short* __restrict__ H) {
    __shared__ __align__(16) unsigned short sA[4096], sB[4096];
    int tid = threadIdx.x;
    int w = tid >> 6, lane = tid & 63;
    int wr = w >> 1, wc = w & 1;
    int lquad = lane >> 4, l15 = lane & 15;
    int mt = blockIdx.x >> 2, nt = blockIdx.x & 3;
    int m0 = mt * 128, n0 = nt * 128;

    int e0 = w * 512 + lane * 8;
    int r0 = e0 >> 5, ce = e0 & 31;
    const unsigned short* gA0 = A + (m0 + r0) * DIM + ce;
    const unsigned short* gA1 = gA0 + 64 * DIM;
    const unsigned short* gB0 = B + (n0 + r0) * DIM + ce;
    const unsigned short* gB1 = gB0 + 64 * DIM;
    unsigned short* lA0 = sA + w * 512;  unsigned short* lA1 = sA + (w + 4) * 512;
    unsigned short* lB0 = sB + w * 512;  unsigned short* lB1 = sB + (w + 4) * 512;

    int offA[4], offB[4];
    #pragma unroll
    for (int i = 0; i < 4; i++) {
        offA[i] = (wr * 64 + i * 16 + l15) * 32 + lquad * 8;
        offB[i] = (wc * 64 + i * 16 + l15) * 32 + lquad * 8;
    }

    f32x4 acc[4][4];
    #pragma unroll
    for (int mi = 0; mi < 4; mi++)
        #pragma unroll
        for (int ni = 0; ni < 4; ni++) acc[mi][ni] = 0;

    for (int kk = 0; kk < 16; kk++) {
        gl_lds16(gA0, lA0); gl_lds16(gA1, lA1);
        gl_lds16(gB0, lB0); gl_lds16(gB1, lB1);
        gA0 += 32; gA1 += 32; gB0 += 32; gB1 += 32;
        __syncthreads();
        short8 af[4], bf_[4];
        #pragma unroll
        for (int i = 0; i < 4; i++) {
            af[i]  = *(const short8*)&sA[offA[i]];
            bf_[i] = *(const short8*)&sB[offB[i]];
        }
        #pragma unroll
        for (int mi = 0; mi < 4; mi++)
            #pragma unroll
            for (int ni = 0; ni < 4; ni++)
                acc[mi][ni] = __builtin_amdgcn_mfma_f32_16x16x32_bf16(af[mi], bf_[ni], acc[mi][ni], 0, 0, 0);
        __syncthreads();
    }

    #pragma unroll
    for (int ni = 0; ni < 4; ni++) {
        int col = n0 + wc * 64 + ni * 16 + l15;
        float bv = b1[col];
        #pragma unroll
        for (int mi = 0; mi < 4; mi++) {
            int rowb = m0 + wr * 64 + mi * 16 + lquad * 4;
            #pragma unroll
            for (int rg = 0; rg < 4; rg++) {
                float v = acc[mi][ni][rg] + bv;
                v = v >= 0.f ? v : NEG * v;
                H[(rowb + rg) * DIM + col] = f2bf(v);
            }
        }
    }
}

// ---------------- GEMM 1: distances -> packed argmin per row ----------------
__launch_bounds__(256, 2)
__global__ void k_dist(const unsigned short* __restrict__ Amel,
                       const unsigned short* __restrict__ Bemb,
                       const float* __restrict__ enorm,
                       unsigned int* __restrict__ p_pmin) {
    __shared__ __align__(16) unsigned short sA[4096], sB[4096];
    __shared__ unsigned int red_pm[256];
    int tid = threadIdx.x;
    int w = tid >> 6, lane = tid & 63;
    int wr = w >> 1, wc = w & 1;
    int lquad = lane >> 4, l15 = lane & 15;
    int mt = blockIdx.x >> 3, split = blockIdx.x & 7;
    int m0 = mt * 128, nbase = split * (NEMB / NSPLIT);

    int e0 = w * 512 + lane * 8;
    int r0 = e0 >> 5, ce = e0 & 31;
    const unsigned short* gA_base = Amel + (m0 + r0) * DIM + ce;
    unsigned short* lA0 = sA + w * 512; unsigned short* lA1 = sA + (w + 4) * 512;
    unsigned short* lB0 = sB + w * 512; unsigned short* lB1 = sB + (w + 4) * 512;

    int offA[4], offB[4];
    #pragma unroll
    for (int i = 0; i < 4; i++) {
        offA[i] = (wr * 64 + i * 16 + l15) * 32 + lquad * 8;
        offB[i] = (wc * 64 + i * 16 + l15) * 32 + lquad * 8;
    }

    unsigned int pmin[16];
    #pragma unroll
    for (int r = 0; r < 16; r++) pmin[r] = 0xFFFFFFFFu;

    for (int nt = 0; nt < 8; nt++) {
        int c0 = nbase + nt * 128;
        const unsigned short* gA = gA_base;
        const unsigned short* gB = Bemb + (c0 + r0) * DIM + ce;

        f32x4 acc[4][4];
        #pragma unroll
        for (int mi = 0; mi < 4; mi++)
            #pragma unroll
            for (int ni = 0; ni < 4; ni++) acc[mi][ni] = 0;

        for (int kk = 0; kk < 16; kk++) {
            gl_lds16(gA, lA0); gl_lds16(gA + 64 * DIM, lA1);
            gl_lds16(gB, lB0); gl_lds16(gB + 64 * DIM, lB1);
            gA += 32; gB += 32;
            __syncthreads();
            short8 af[4], bf_[4];
            #pragma unroll
            for (int i = 0; i < 4; i++) {
                af[i]  = *(const short8*)&sA[offA[i]];
                bf_[i] = *(const short8*)&sB[offB[i]];
            }
            #pragma unroll
            for (int mi = 0; mi < 4; mi++)
                #pragma unroll
                for (int ni = 0; ni < 4; ni++)
                    acc[mi][ni] = __builtin_amdgcn_mfma_f32_16x16x32_bf16(af[mi], bf_[ni], acc[mi][ni], 0, 0, 0);
            __syncthreads();
        }

        float en[4]; unsigned int cl[4];
        #pragma unroll
        for (int ni = 0; ni < 4; ni++) {
            int col = c0 + wc * 64 + ni * 16 + l15;
            cl[ni] = (unsigned int)col;
            en[ni] = enorm[col] - 512.0f;   // recentre near 0 for key precision
        }
        #pragma unroll
        for (int mi = 0; mi < 4; mi++)
            #pragma unroll
            for (int rg = 0; rg < 4; rg++) {
                int r = mi * 4 + rg;
                #pragma unroll
                for (int ni = 0; ni < 4; ni++) {
                    float d = fmaf(-2.f, acc[mi][ni][rg], en[ni]);
                    unsigned int pk = (fkey(d) & 0xFFFFE000u) | cl[ni];
                    pmin[r] = pmin[r] < pk ? pmin[r] : pk;
                }
            }
    }

    #pragma unroll
    for (int r = 0; r < 16; r++)
        #pragma unroll
        for (int d = 1; d < 16; d <<= 1) {
            unsigned int o = (unsigned int)__shfl_xor((int)pmin[r], d);
            pmin[r] = pmin[r] < o ? pmin[r] : o;
        }
    if (l15 == 0) {
        #pragma unroll
        for (int mi = 0; mi < 4; mi++)
            #pragma unroll
            for (int rg = 0; rg < 4; rg++)
                red_pm[(wr * 64 + mi * 16 + lquad * 4 + rg) * 2 + wc] = pmin[mi * 4 + rg];
    }
    __syncthreads();
    if (tid < 128) {
        unsigned int a = red_pm[2 * tid], b = red_pm[2 * tid + 1];
        p_pmin[split * BSZ + m0 + tid] = a < b ? a : b;
    }
}

// ---------------- GEMM 2: logits -> sum(exp) + packed argmax per row ----------------
__launch_bounds__(256, 2)
__global__ void k_logits(const unsigned short* __restrict__ Ah,
                         const unsigned short* __restrict__ Bw2,
                         const float* __restrict__ b2,
                         float* __restrict__ p_s,
                         unsigned int* __restrict__ p_pmax) {
    __shared__ __align__(16) unsigned short sA[4096], sB[4096];
    __shared__ float red_s[256];
    __shared__ unsigned int red_pm[256];
    int tid = threadIdx.x;
    int w = tid >> 6, lane = tid & 63;
    int wr = w >> 1, wc = w & 1;
    int lquad = lane >> 4, l15 = lane & 15;
    int mt = blockIdx.x >> 3, split = blockIdx.x & 7;
    int m0 = mt * 128, nbase = split * (NEMB / NSPLIT);

    int e0 = w * 512 + lane * 8;
    int r0 = e0 >> 5, ce = e0 & 31;
    const unsigned short* gA_base = Ah + (m0 + r0) * DIM + ce;
    unsigned short* lA0 = sA + w * 512; unsigned short* lA1 = sA + (w + 4) * 512;
    unsigned short* lB0 = sB + w * 512; unsigned short* lB1 = sB + (w + 4) * 512;

    int offA[4], offB[4];
    #pragma unroll
    for (int i = 0; i < 4; i++) {
        offA[i] = (wr * 64 + i * 16 + l15) * 32 + lquad * 8;
        offB[i] = (wc * 64 + i * 16 + l15) * 32 + lquad * 8;
    }

    float s[16];
    unsigned int pmax[16];
    #pragma unroll
    for (int r = 0; r < 16; r++) { s[r] = 0.f; pmax[r] = 0u; }

    for (int nt = 0; nt < 8; nt++) {
        int c0 = nbase + nt * 128;
        const unsigned short* gA = gA_base;
        const unsigned short* gB = Bw2 + (c0 + r0) * DIM + ce;

        f32x4 acc[4][4];
        #pragma unroll
        for (int mi = 0; mi < 4; mi++)
            #pragma unroll
            for (int ni = 0; ni < 4; ni++) acc[mi][ni] = 0;

        for (int kk = 0; kk < 16; kk++) {
            gl_lds16(gA, lA0); gl_lds16(gA + 64 * DIM, lA1);
            gl_lds16(gB, lB0); gl_lds16(gB + 64 * DIM, lB1);
            gA += 32; gB += 32;
            __syncthreads();
            short8 af[4], bf_[4];
            #pragma unroll
            for (int i = 0; i < 4; i++) {
                af[i]  = *(const short8*)&sA[offA[i]];
                bf_[i] = *(const short8*)&sB[offB[i]];
            }
            #pragma unroll
            for (int mi = 0; mi < 4; mi++)
                #pragma unroll
                for (int ni = 0; ni < 4; ni++)
                    acc[mi][ni] = __builtin_amdgcn_mfma_f32_16x16x32_bf16(af[mi], bf_[ni], acc[mi][ni], 0, 0, 0);
            __syncthreads();
        }

        float bb[4]; unsigned int ic[4];
        #pragma unroll
        for (int ni = 0; ni < 4; ni++) {
            int col = c0 + wc * 64 + ni * 16 + l15;
            bb[ni] = b2[col];
            ic[ni] = (unsigned int)(NEMB - 1 - col);  // complemented so max => smallest col
        }
        #pragma unroll
        for (int mi = 0; mi < 4; mi++)
            #pragma unroll
            for (int rg = 0; rg < 4; rg++) {
                int r = mi * 4 + rg;
                #pragma unroll
                for (int ni = 0; ni < 4; ni++) {
                    float logit = acc[mi][ni][rg] + bb[ni];
                    s[r] += __expf(logit);      // logits are O(1): no max-shift needed
                    unsigned int pk = (fkey(logit) & 0xFFFFE000u) | ic[ni];
                    pmax[r] = pmax[r] > pk ? pmax[r] : pk;
                }
            }
    }

    #pragma unroll
    for (int r = 0; r < 16; r++)
        #pragma unroll
        for (int d = 1; d < 16; d <<= 1) {
            s[r] += __shfl_xor(s[r], d);
            unsigned int o = (unsigned int)__shfl_xor((int)pmax[r], d);
            pmax[r] = pmax[r] > o ? pmax[r] : o;
        }
    if (l15 == 0) {
        #pragma unroll
        for (int mi = 0; mi < 4; mi++)
            #pragma unroll
            for (int rg = 0; rg < 4; rg++) {
                int r2 = (wr * 64 + mi * 16 + lquad * 4 + rg) * 2 + wc;
                red_s[r2] = s[mi * 4 + rg];
                red_pm[r2] = pmax[mi * 4 + rg];
            }
    }
    __syncthreads();
    if (tid < 128) {
        float S = red_s[2 * tid] + red_s[2 * tid + 1];
        unsigned int a = red_pm[2 * tid], b = red_pm[2 * tid + 1];
        int pidx = split * BSZ + m0 + tid;
        p_s[pidx] = S;
        p_pmax[pidx] = a > b ? a : b;
    }
}

// ---------------- merge split partials per row ----------------
__global__ void k_merge(const float* __restrict__ p_s, const unsigned int* __restrict__ p_pmax,
                        const unsigned int* __restrict__ p_pmin,
                        int* __restrict__ mel_idx, float* __restrict__ lse,
                        float* __restrict__ match) {
    int r = blockIdx.x * blockDim.x + threadIdx.x;
    if (r >= BSZ) return;
    float S = 0.f; unsigned int PM = 0u, PN = 0xFFFFFFFFu;
    #pragma unroll
    for (int sp = 0; sp < NSPLIT; sp++) {
        S += p_s[sp * BSZ + r];
        unsigned int a = p_pmax[sp * BSZ + r];
        PM = PM > a ? PM : a;
        unsigned int b = p_pmin[sp * BSZ + r];
        PN = PN < b ? PN : b;
    }
    int eidx = (NEMB - 1) - (int)(PM & 0x1FFFu);
    int midx = (int)(PN & 0x1FFFu);
    mel_idx[r] = midx;
    lse[r] = __logf(S);
    match[r] = (eidx == midx) ? 1.f : 0.f;
}

// ---------------- gather picked logit, per-row loss ----------------
__device__ __forceinline__ float dot2bf(unsigned int h, unsigned int w) {
    return bf2f((unsigned short)(h & 0xffff)) * bf2f((unsigned short)(w & 0xffff))
         + bf2f((unsigned short)(h >> 16))    * bf2f((unsigned short)(w >> 16));
}

__global__ void k_gather(const unsigned short* __restrict__ H,
                         const unsigned short* __restrict__ W2b,
                         const float* __restrict__ b2,
                         const int* __restrict__ mel_idx,
                         const float* __restrict__ lse,
                         float* __restrict__ loss) {
    int r = blockIdx.x * 4 + (threadIdx.x >> 6);
    int lane = threadIdx.x & 63;
    int idx = mel_idx[r];
    uint4 hv = *(const uint4*)(H + r * DIM + lane * 8);
    uint4 wv = *(const uint4*)(W2b + idx * DIM + lane * 8);
    float s = dot2bf(hv.x, wv.x) + dot2bf(hv.y, wv.y) + dot2bf(hv.z, wv.z) + dot2bf(hv.w, wv.w);
    #pragma unroll
    for (int d = 1; d < 64; d <<= 1) s += __shfl_xor(s, d);
    if (lane == 0) loss[r] = lse[r] - (s + b2[idx]);
}

// ---------------- final scalar reduction ----------------
__global__ void k_reduce(const float* __restrict__ loss, const float* __restrict__ match,
                         float* __restrict__ out) {
    __shared__ float sl[256], sm[256];
    int tid = threadIdx.x;
    float a = 0.f, b = 0.f;
    for (int i = tid; i < BSZ; i += 256) { a += loss[i]; b += match[i]; }
    sl[tid] = a; sm[tid] = b;
    __syncthreads();
    for (int s = 128; s > 0; s >>= 1) {
        if (tid < s) { sl[tid] += sl[tid + s]; sm[tid] += sm[tid + s]; }
        __syncthreads();
    }
    if (tid == 0) { out[0] = sl[0] / (float)BSZ; out[1] = sm[0] / (float)BSZ; }
}

extern "C" void kernel_launch(void* const* d_in, const int* in_sizes, int n_in,
                              void* d_out, int out_size, void* d_ws, size_t ws_size,
                              hipStream_t stream) {
    const float* eeg = (const float*)d_in[0];
    const float* mel = (const float*)d_in[1];
    const float* emb = (const float*)d_in[2];
    const float* W1  = (const float*)d_in[3];
    const float* b1  = (const float*)d_in[4];
    const float* W2  = (const float*)d_in[5];
    const float* b2  = (const float*)d_in[6];
    float* out = (float*)d_out;

    unsigned short* ws_mel = (unsigned short*)d_ws;
    unsigned short* ws_eeg = ws_mel + (size_t)BSZ * DIM;
    unsigned short* ws_h   = ws_eeg + (size_t)BSZ * DIM;
    unsigned short* ws_emb = ws_h   + (size_t)BSZ * DIM;
    unsigned short* ws_w2  = ws_emb + (size_t)NEMB * DIM;
    unsigned short* ws_w1  = ws_w2  + (size_t)NEMB * DIM;
    float* ws_en  = (float*)(ws_w1 + (size_t)DIM * DIM);
    float* p_s    = ws_en + NEMB;
    unsigned int* p_pmax = (unsigned int*)(p_s + (size_t)NSPLIT * BSZ);
    unsigned int* p_pmin = p_pmax + (size_t)NSPLIT * BSZ;
    int*   mel_i  = (int*)(p_pmin + (size_t)NSPLIT * BSZ);
    float* lse    = (float*)(mel_i + BSZ);
    float* match  = lse + BSZ;
    float* loss   = match + BSZ;

    k_convert_all<<<1024, 256, 0, stream>>>(eeg, mel, emb, W2, W1,
                                            ws_eeg, ws_mel, ws_emb, ws_w2, ws_w1);
    k_enorm<<<NEMB / 4, 256, 0, stream>>>(emb, ws_en);
    k_hgemm<<<(BSZ / 128) * (DIM / 128), 256, 0, stream>>>(ws_eeg, ws_w1, b1, ws_h);
    k_dist<<<(BSZ / 128) * NSPLIT, 256, 0, stream>>>(ws_mel, ws_emb, ws_en, p_pmin);
    k_logits<<<(BSZ / 128) * NSPLIT, 256, 0, stream>>>(ws_h, ws_w2, b2, p_s, p_pmax);
    k_merge<<<BSZ / 256, 256, 0, stream>>>(p_s, p_pmax, p_pmin, mel_i, lse, match);
    k_gather<<<BSZ / 4, 256, 0, stream>>>(ws_h, ws_w2, b2, mel_i, lse, loss);
    k_reduce<<<1, 256, 0, stream>>>(loss, match, out);
}